// Round 5
// baseline (263.701 us; speedup 1.0000x reference)
//
#include <hip/hip_runtime.h>

// Positional encoding off-grid: out[c, i] layout (256, num), row-major, fp32.
//   c in [0,128):   c=2k -> sin(y_i * f_k), c=2k+1 -> cos(y_i * f_k)
//   c in [128,256): c-128=2k -> sin(x_i * f_k), else cos(x_i * f_k)
//
// Write-BW bound: 268 MB out, ~2 MB in. Floor ~41-43 us @ 6.3-6.5 TB/s.
//
// R1 result: k-loop sweep == R0 row-slice structure within 0.7% total.
// Accounting: total 255 us = 162 (1 GiB ws poison fill) + ~41 (256 MiB out
// poison fill) + ~43 kernel + launch => kernel likely already at write floor.
//
// R2: infra failure. R3: nt builtin rejects HIP float4*. R4: ext_vector
// elements aren't addressable (&s.y illegal). R5: sincos into scalars,
// assemble ext_vector, nt-store. Discriminator: if the kernel was
// L2-write-interference-limited, nt stores bypass L2 and total drops
// ~40 us; if unchanged, kernel is at the write roofline and the remaining
// ~210 us is mandatory harness poison.

typedef float f32x4 __attribute__((ext_vector_type(4)));

__global__ __launch_bounds__(256) void pe_offgrid_kernel(
    const float* __restrict__ YX,        // (2, num)
    const float* __restrict__ inv_freq,  // (64,)
    float* __restrict__ out,             // (256, num)
    int num)
{
    __shared__ float fshared[64];
    if (threadIdx.x < 64) fshared[threadIdx.x] = inv_freq[threadIdx.x];
    __syncthreads();

    const int i4 = blockIdx.x * blockDim.x + threadIdx.x;  // float4 chunk over i
    if (4 * i4 >= num) return;

    const bool isY = (blockIdx.y == 0);

    // coord values for the 4 consecutive i's this thread owns (read ONCE,
    // reused for all 64 frequencies)
    const f32x4 c4 = ((const f32x4*)(YX + (isY ? 0 : num)))[i4];
    const float cx = c4.x, cy = c4.y, cz = c4.z, cw = c4.w;

    float* base = out + (isY ? (size_t)0 : (size_t)128 * (size_t)num)
                      + (size_t)(4 * i4);
    const size_t rowStep = 2 * (size_t)num;   // advance 2 rows per k

#pragma unroll 8
    for (int k = 0; k < 64; ++k) {
        const float fr = fshared[k];

        float s0, s1, s2, s3, c0, c1, c2, c3;
        __sincosf(cx * fr, &s0, &c0);
        __sincosf(cy * fr, &s1, &c1);
        __sincosf(cz * fr, &s2, &c2);
        __sincosf(cw * fr, &s3, &c3);

        f32x4 s, c;
        s.x = s0; s.y = s1; s.z = s2; s.w = s3;
        c.x = c0; c.y = c1; c.z = c2; c.w = c3;

        float* p = base + (size_t)k * rowStep;
        // nontemporal: output is streaming write-once, bypass L2
        __builtin_nontemporal_store(s, (f32x4*)(p));
        __builtin_nontemporal_store(c, (f32x4*)(p + num));
    }
}

extern "C" void kernel_launch(void* const* d_in, const int* in_sizes, int n_in,
                              void* d_out, int out_size, void* d_ws, size_t ws_size,
                              hipStream_t stream) {
    const float* YX       = (const float*)d_in[0];
    const float* inv_freq = (const float*)d_in[1];
    float* out            = (float*)d_out;

    const int num = in_sizes[0] / 2;          // 262144
    const int i4_total = (num + 3) / 4;       // 65536
    dim3 block(256);
    dim3 grid((i4_total + block.x - 1) / block.x, 2);  // 512 blocks, 2/CU
    pe_offgrid_kernel<<<grid, block, 0, stream>>>(YX, inv_freq, out, num);
}

// Round 6
// 256.354 us; speedup vs baseline: 1.0287x; 1.0287x over previous
//
#include <hip/hip_runtime.h>

// Positional encoding off-grid: out[c, i] layout (256, num), row-major, fp32.
//   c in [0,128):   c=2k -> sin(y_i * f_k), c=2k+1 -> cos(y_i * f_k)
//   c in [128,256): c-128=2k -> sin(x_i * f_k), else cos(x_i * f_k)
//
// ROOFLINE CONCLUSION (R0-R5):
//   Mandatory output write: 256 rows x 1 MiB = 268.4 MB fp32 => 41.3 us
//   floor @ 6.5 TB/s (fill-measured achievable). Timed graph = 162 us
//   (1 GiB ws poison fill) + ~41 us (out poison fill) + kernel(~45-50) +
//   launch ~= 255 us. Three structurally different store schedules were
//   indistinguishable:
//     R0  8 row-slices, full residency (scattered writes)   255.2 us
//     R1  k-sweep, dense sliding window                     257.0 us
//     R5  R1 + nontemporal (L2-bypass) stores               263.7 us (slow
//         session: fills also -4%; nt neutral-to-negative)
//   => kernel is write-BW-bound at the floor; L2-interference hypothesis
//   refuted; compute (~4 us of sincos on TRANS pipe) irrelevant.
// This file is the best-measured variant: R1 structure, plain stores.

__global__ __launch_bounds__(256) void pe_offgrid_kernel(
    const float* __restrict__ YX,        // (2, num)
    const float* __restrict__ inv_freq,  // (64,)
    float* __restrict__ out,             // (256, num)
    int num)
{
    __shared__ float fshared[64];
    if (threadIdx.x < 64) fshared[threadIdx.x] = inv_freq[threadIdx.x];
    __syncthreads();

    const int i4 = blockIdx.x * blockDim.x + threadIdx.x;  // float4 chunk over i
    if (4 * i4 >= num) return;

    const bool isY = (blockIdx.y == 0);

    // coord values for the 4 consecutive i's this thread owns (read ONCE,
    // reused for all 64 frequencies)
    const float4 c4 = ((const float4*)(YX + (isY ? 0 : num)))[i4];

    float* base = out + (isY ? (size_t)0 : (size_t)128 * (size_t)num)
                      + (size_t)(4 * i4);
    const size_t rowStep = 2 * (size_t)num;   // advance 2 rows per k

#pragma unroll 8
    for (int k = 0; k < 64; ++k) {
        const float fr = fshared[k];

        float4 s, c;
        __sincosf(c4.x * fr, &s.x, &c.x);
        __sincosf(c4.y * fr, &s.y, &c.y);
        __sincosf(c4.z * fr, &s.z, &c.z);
        __sincosf(c4.w * fr, &s.w, &c.w);

        float* p = base + (size_t)k * rowStep;
        *(float4*)(p)       = s;   // sin row (c = 2k [+128])
        *(float4*)(p + num) = c;   // cos row (c = 2k+1 [+128])
    }
}

extern "C" void kernel_launch(void* const* d_in, const int* in_sizes, int n_in,
                              void* d_out, int out_size, void* d_ws, size_t ws_size,
                              hipStream_t stream) {
    const float* YX       = (const float*)d_in[0];
    const float* inv_freq = (const float*)d_in[1];
    float* out            = (float*)d_out;

    const int num = in_sizes[0] / 2;          // 262144
    const int i4_total = (num + 3) / 4;       // 65536
    dim3 block(256);
    dim3 grid((i4_total + block.x - 1) / block.x, 2);  // 512 blocks, 2/CU
    pe_offgrid_kernel<<<grid, block, 0, stream>>>(YX, inv_freq, out, num);
}